// Round 5
// baseline (714.406 us; speedup 1.0000x reference)
//
#include <hip/hip_runtime.h>

#define F 128
#define NN 100000
#define NBUK 782  // ceil(NN/128)
#define LD 136   // padded LDS row stride in bf16 elems (272 B)

typedef __attribute__((ext_vector_type(8))) short short8;   // 8 bf16 = 16 B
typedef __attribute__((ext_vector_type(4))) float f32x4;
typedef __attribute__((ext_vector_type(4))) unsigned short us4;
typedef unsigned short ushort_t;

// ---------------------------------------------------------------------------
// bf16 helpers (RNE)
// ---------------------------------------------------------------------------
__device__ __forceinline__ ushort_t f2b(float f) {
    union { float f; unsigned u; } x;
    x.f = f;
    unsigned r = x.u + 0x7fffu + ((x.u >> 16) & 1u);
    return (ushort_t)(r >> 16);
}
__device__ __forceinline__ float b2f(ushort_t u) {
    union { unsigned u; float f; } x;
    x.u = ((unsigned)u) << 16;
    return x.f;
}

// ---------------------------------------------------------------------------
// Bucketed CSR build. Bucket = dst>>7 (128 nodes per bucket).
// Replaces global count + 3x N-wide scans + random-write fill (whose 105 MB
// WRITE_SIZE was the round-4 bottleneck).
// ---------------------------------------------------------------------------
__global__ __launch_bounds__(256) void bucket_count(const int* __restrict__ dst,
                                                    int* __restrict__ bcnt, int E) {
    __shared__ int h[NBUK];
    for (int i = threadIdx.x; i < NBUK; i += 256) h[i] = 0;
    __syncthreads();
    const int stride = gridDim.x * 256;
    for (int i = blockIdx.x * 256 + threadIdx.x; i < E; i += stride)
        atomicAdd(&h[dst[i] >> 7], 1);
    __syncthreads();
    for (int i = threadIdx.x; i < NBUK; i += 256)
        if (h[i]) atomicAdd(&bcnt[i], h[i]);
}

__global__ __launch_bounds__(1024) void bucket_scan(const int* __restrict__ bcnt,
                                                    int* __restrict__ boffs,
                                                    int* __restrict__ bcur, int E) {
    __shared__ int s[1024];
    const int t = threadIdx.x;
    int v = (t < NBUK) ? bcnt[t] : 0;
    s[t] = v;
    __syncthreads();
    for (int d = 1; d < 1024; d <<= 1) {
        int u = (t >= d) ? s[t - d] : 0;
        __syncthreads();
        s[t] += u;
        __syncthreads();
    }
    if (t < NBUK) {
        int o = s[t] - v;  // exclusive
        boffs[t] = o;
        bcur[t] = o;
    }
    if (t == 0) boffs[NBUK] = E;
}

// scatter packed (dstlo<<20 | src) into bucket regions; writes cluster around
// 782 sequential cursors -> full-line writebacks (no 16x amplification).
__global__ void bucket_scatter(const int* __restrict__ src, const int* __restrict__ dst,
                               int* __restrict__ bcur, unsigned* __restrict__ pairs, int E) {
    int i = blockIdx.x * blockDim.x + threadIdx.x;
    if (i < E) {
        const int d = dst[i];
        const int p = atomicAdd(&bcur[d >> 7], 1);
        pairs[p] = ((unsigned)(d & 127) << 20) | (unsigned)src[i];
    }
}

// per-bucket counting sort, all random work in LDS; csr/offs writes sequential.
__global__ __launch_bounds__(256) void bucket_sort(const unsigned* __restrict__ pairs,
                                                   const int* __restrict__ boffs,
                                                   int* __restrict__ offs,
                                                   int* __restrict__ csr) {
    __shared__ int cnt[128], loffs[128], lcur[128];
    const int b = blockIdx.x, t = threadIdx.x;
    const int e0 = boffs[b], e1 = boffs[b + 1];
    const int node0 = b << 7;
    const int nnode = min(128, NN - node0);
    if (t < 128) cnt[t] = 0;
    __syncthreads();
    for (int i = e0 + t; i < e1; i += 256) atomicAdd(&cnt[pairs[i] >> 20], 1);
    __syncthreads();
    if (t < 128) loffs[t] = cnt[t];
    __syncthreads();
    for (int d = 1; d < 128; d <<= 1) {
        int u = (t >= d && t < 128) ? loffs[t - d] : 0;
        __syncthreads();
        if (t < 128) loffs[t] += u;
        __syncthreads();
    }
    if (t < 128) {
        const int ex = loffs[t] - cnt[t];  // exclusive
        lcur[t] = e0 + ex;
        if (t < nnode) offs[node0 + t] = e0 + ex;
    }
    if (b == NBUK - 1 && t == 0) offs[NN] = e1;
    __syncthreads();
    for (int i = e0 + t; i < e1; i += 256) {
        const unsigned v = pairs[i];
        const int p = atomicAdd(&lcur[v >> 20], 1);
        csr[p] = (int)(v & 0xFFFFFu);
    }
}

// ---------------------------------------------------------------------------
// prepass: fp32 -> bf16 convert (4 elems/thread)
// ---------------------------------------------------------------------------
__global__ void cvt_kernel(const float* __restrict__ X, ushort_t* __restrict__ Y, int n4) {
    int i = blockIdx.x * blockDim.x + threadIdx.x;
    if (i < n4) {
        float4 v = ((const float4*)X)[i];
        us4 o;
        o.x = f2b(v.x); o.y = f2b(v.y); o.z = f2b(v.z); o.w = f2b(v.w);
        ((us4*)Y)[i] = o;
    }
}

// ---------------------------------------------------------------------------
// prepass: all four W [k][n] fp32 -> WT [n][k] bf16 in one launch (64 blocks)
// ---------------------------------------------------------------------------
__global__ __launch_bounds__(256) void wt_all(
    const float* __restrict__ Wa, const float* __restrict__ Wb,
    const float* __restrict__ Wc, const float* __restrict__ Wd,
    ushort_t* __restrict__ Oa, ushort_t* __restrict__ Ob,
    ushort_t* __restrict__ Oc, ushort_t* __restrict__ Od) {
    __shared__ float tile[32][33];
    const int m = blockIdx.x >> 4;
    const int b = blockIdx.x & 15;
    const float* W = (m == 0) ? Wa : (m == 1) ? Wb : (m == 2) ? Wc : Wd;
    ushort_t* WT = (m == 0) ? Oa : (m == 1) ? Ob : (m == 2) ? Oc : Od;
    const int by = (b >> 2) * 32;  // k base
    const int bx = (b & 3) * 32;   // n base
    const int tx = threadIdx.x & 31, ty = threadIdx.x >> 5;  // 32 x 8
    for (int i = 0; i < 32; i += 8)
        tile[ty + i][tx] = W[(by + ty + i) * F + bx + tx];
    __syncthreads();
    for (int i = 0; i < 32; i += 8)
        WT[(bx + ty + i) * F + by + tx] = f2b(tile[tx][ty + i]);
}

// ---------------------------------------------------------------------------
// fused SAGE layer (bf16 MFMA) — unchanged from round 4 (passed, absmax .031)
// ---------------------------------------------------------------------------
template <typename TOUT>
__device__ __forceinline__ void store1(TOUT* p, float v);
template <> __device__ __forceinline__ void store1<float>(float* p, float v) { *p = v; }
template <> __device__ __forceinline__ void store1<ushort_t>(ushort_t* p, float v) { *p = f2b(v); }

template <typename TOUT>
__global__ __launch_bounds__(256, 6) void sage_layer(
    const ushort_t* __restrict__ Xg,
    const int* __restrict__ offs, const int* __restrict__ csr,
    const ushort_t* __restrict__ WTs, const ushort_t* __restrict__ WTn,
    const float* __restrict__ bias,
    TOUT* __restrict__ out, int relu) {
    __shared__ __align__(16) ushort_t sX[32 * LD];
    __shared__ __align__(16) ushort_t sH[32 * LD];
    const int t = threadIdx.x;
    const int lane = t & 63;
    const int wave = t >> 6;
    const int brow0 = blockIdx.x * 32;

    // Phase 0: stage self rows
    {
        const ushort_t* base = Xg + (size_t)brow0 * F;
        for (int i = t; i < 32 * 16; i += 256) {
            int row = i >> 4, ch = i & 15;
            *(short8*)&sX[row * LD + ch * 8] = *(const short8*)&base[row * F + ch * 8];
        }
    }

    // Phase A: neighbor mean -> sH (4 slots x 16 lanes; unroll 4)
    {
        const int slot = lane >> 4;
        const int cl = lane & 15;
        const int c8 = cl * 8;
#pragma unroll
        for (int rr = 0; rr < 2; rr++) {
            const int rloc = wave * 8 + slot * 2 + rr;
            const int row = brow0 + rloc;
            const int e0 = offs[row], e1 = offs[row + 1];
            float a0[8], a1[8], a2[8], a3[8];
#pragma unroll
            for (int j = 0; j < 8; j++) { a0[j] = a1[j] = a2[j] = a3[j] = 0.f; }
            int e = e0;
            for (; e + 3 < e1; e += 4) {
                const int s0 = csr[e], s1 = csr[e + 1], s2 = csr[e + 2], s3 = csr[e + 3];
                const short8 v0 = *(const short8*)&Xg[(size_t)s0 * F + c8];
                const short8 v1 = *(const short8*)&Xg[(size_t)s1 * F + c8];
                const short8 v2 = *(const short8*)&Xg[(size_t)s2 * F + c8];
                const short8 v3 = *(const short8*)&Xg[(size_t)s3 * F + c8];
#pragma unroll
                for (int j = 0; j < 8; j++) {
                    a0[j] += b2f((ushort_t)v0[j]);
                    a1[j] += b2f((ushort_t)v1[j]);
                    a2[j] += b2f((ushort_t)v2[j]);
                    a3[j] += b2f((ushort_t)v3[j]);
                }
            }
            for (; e < e1; e++) {
                const int s0 = csr[e];
                const short8 v0 = *(const short8*)&Xg[(size_t)s0 * F + c8];
#pragma unroll
                for (int j = 0; j < 8; j++) a0[j] += b2f((ushort_t)v0[j]);
            }
            const float inv = (e1 > e0) ? (1.0f / (float)(e1 - e0)) : 0.f;
            short8 o;
#pragma unroll
            for (int j = 0; j < 8; j++)
                o[j] = (short)f2b(((a0[j] + a1[j]) + (a2[j] + a3[j])) * inv);
            *(short8*)&sH[rloc * LD + c8] = o;
        }
    }
    __syncthreads();

    // Phase B: MFMA GEMM (wave strip: 32 rows x 32 cols)
    const int q = lane >> 4, nl = lane & 15;
    const int colbase = wave * 32;
    f32x4 acc00 = (f32x4)0.f, acc01 = (f32x4)0.f, acc10 = (f32x4)0.f, acc11 = (f32x4)0.f;
#pragma unroll
    for (int ks = 0; ks < 4; ks++) {
        const int ko = ks * 32 + q * 8;
        const short8 aS0 = *(const short8*)&sX[nl * LD + ko];
        const short8 aS1 = *(const short8*)&sX[(16 + nl) * LD + ko];
        const short8 aN0 = *(const short8*)&sH[nl * LD + ko];
        const short8 aN1 = *(const short8*)&sH[(16 + nl) * LD + ko];
        const size_t bo0 = (size_t)(colbase + nl) * F + ko;
        const size_t bo1 = (size_t)(colbase + 16 + nl) * F + ko;
        const short8 bS0 = *(const short8*)&WTs[bo0];
        const short8 bS1 = *(const short8*)&WTs[bo1];
        const short8 bN0 = *(const short8*)&WTn[bo0];
        const short8 bN1 = *(const short8*)&WTn[bo1];
        acc00 = __builtin_amdgcn_mfma_f32_16x16x32_bf16(aS0, bS0, acc00, 0, 0, 0);
        acc00 = __builtin_amdgcn_mfma_f32_16x16x32_bf16(aN0, bN0, acc00, 0, 0, 0);
        acc01 = __builtin_amdgcn_mfma_f32_16x16x32_bf16(aS0, bS1, acc01, 0, 0, 0);
        acc01 = __builtin_amdgcn_mfma_f32_16x16x32_bf16(aN0, bN1, acc01, 0, 0, 0);
        acc10 = __builtin_amdgcn_mfma_f32_16x16x32_bf16(aS1, bS0, acc10, 0, 0, 0);
        acc10 = __builtin_amdgcn_mfma_f32_16x16x32_bf16(aN1, bN0, acc10, 0, 0, 0);
        acc11 = __builtin_amdgcn_mfma_f32_16x16x32_bf16(aS1, bS1, acc11, 0, 0, 0);
        acc11 = __builtin_amdgcn_mfma_f32_16x16x32_bf16(aN1, bN1, acc11, 0, 0, 0);
    }

    // Epilogue: C/D layout col=lane&15, row=(lane>>4)*4+reg
    const float b0 = bias[colbase + nl];
    const float b1 = bias[colbase + 16 + nl];
#pragma unroll
    for (int r = 0; r < 4; r++) {
        const int orow0 = brow0 + q * 4 + r;
        const int orow1 = brow0 + 16 + q * 4 + r;
        float v00 = acc00[r] + b0, v01 = acc01[r] + b1;
        float v10 = acc10[r] + b0, v11 = acc11[r] + b1;
        if (relu) {
            v00 = fmaxf(v00, 0.f); v01 = fmaxf(v01, 0.f);
            v10 = fmaxf(v10, 0.f); v11 = fmaxf(v11, 0.f);
        }
        store1<TOUT>(&out[(size_t)orow0 * F + colbase + nl], v00);
        store1<TOUT>(&out[(size_t)orow0 * F + colbase + 16 + nl], v01);
        store1<TOUT>(&out[(size_t)orow1 * F + colbase + nl], v10);
        store1<TOUT>(&out[(size_t)orow1 * F + colbase + 16 + nl], v11);
    }
}

// ---------------------------------------------------------------------------
extern "C" void kernel_launch(void* const* d_in, const int* in_sizes, int n_in,
                              void* d_out, int out_size, void* d_ws, size_t ws_size,
                              hipStream_t stream) {
    const float* x = (const float*)d_in[0];
    const int* src = (const int*)d_in[1];
    const int* dst = (const int*)d_in[2];
    const float* W1s = (const float*)d_in[3];
    const float* W1n = (const float*)d_in[4];
    const float* b1 = (const float*)d_in[5];
    const float* W2s = (const float*)d_in[6];
    const float* W2n = (const float*)d_in[7];
    const float* b2 = (const float*)d_in[8];
    float* out = (float*)d_out;

    const int E = in_sizes[1];
    const int N = NN;
    const int E4 = (E + 3) & ~3;

    // ws layout (~39 MB < proven-safe budget):
    //   pairs[E] u32 | csr[E] int | h1[N*F] bf16 | WT 4*F*F bf16 |
    //   offs[N+1] | bcnt[NBUK] | boffs[NBUK+1] | bcur[NBUK]
    unsigned* pairs = (unsigned*)d_ws;
    int* csr = (int*)(pairs + E4);
    ushort_t* h1 = (ushort_t*)(csr + E4);
    ushort_t* WT1s = h1 + (size_t)N * F;
    ushort_t* WT1n = WT1s + F * F;
    ushort_t* WT2s = WT1n + F * F;
    ushort_t* WT2n = WT2s + F * F;
    int* offs = (int*)(WT2n + F * F);
    int* bcnt = offs + (N + 1);
    int* boffs = bcnt + NBUK;
    int* bcur = boffs + (NBUK + 1);
    // x_bf16 lives in d_out: dead by the time layer 2 overwrites d_out.
    ushort_t* xb = (ushort_t*)d_out;

    hipMemsetAsync(bcnt, 0, NBUK * sizeof(int), stream);
    bucket_count<<<512, 256, 0, stream>>>(dst, bcnt, E);
    bucket_scan<<<1, 1024, 0, stream>>>(bcnt, boffs, bcur, E);
    bucket_scatter<<<(E + 255) / 256, 256, 0, stream>>>(src, dst, bcur, pairs, E);
    bucket_sort<<<NBUK, 256, 0, stream>>>(pairs, boffs, offs, csr);

    // prepasses: x -> bf16 (into d_out), weights -> bf16 transposed
    cvt_kernel<<<(N * F / 4 + 255) / 256, 256, 0, stream>>>(x, xb, N * F / 4);
    wt_all<<<64, 256, 0, stream>>>(W1s, W1n, W2s, W2n, WT1s, WT1n, WT2s, WT2n);

    // layer 1: bf16 in (xb), bf16 h1 out, relu
    sage_layer<ushort_t><<<N / 32, 256, 0, stream>>>(
        xb, offs, csr, WT1s, WT1n, b1, h1, 1);
    // layer 2: bf16 in (h1), fp32 out
    sage_layer<float><<<N / 32, 256, 0, stream>>>(
        h1, offs, csr, WT2s, WT2n, b2, out, 0);
}

// Round 6
// 368.440 us; speedup vs baseline: 1.9390x; 1.9390x over previous
//
#include <hip/hip_runtime.h>

#define F 128
#define NN 100000
#define NBUK 782   // ceil(NN/128), 128 nodes per bucket
#define NBLK 128   // sort chunks; 12500 edges/chunk -> avg run = 16 edges = 64 B
#define LD 136     // padded LDS row stride in bf16 elems (272 B)

typedef __attribute__((ext_vector_type(8))) short short8;   // 8 bf16 = 16 B
typedef __attribute__((ext_vector_type(4))) float f32x4;
typedef __attribute__((ext_vector_type(4))) unsigned short us4;
typedef unsigned short ushort_t;

// ---------------------------------------------------------------------------
// bf16 helpers (RNE)
// ---------------------------------------------------------------------------
__device__ __forceinline__ ushort_t f2b(float f) {
    union { float f; unsigned u; } x;
    x.f = f;
    unsigned r = x.u + 0x7fffu + ((x.u >> 16) & 1u);
    return (ushort_t)(r >> 16);
}
__device__ __forceinline__ float b2f(ushort_t u) {
    union { unsigned u; float f; } x;
    x.u = ((unsigned)u) << 16;
    return x.f;
}

// ---------------------------------------------------------------------------
// CSR build v3: contention-free counting sort.
// Round-5 forensics: 1.6M global atomics on 782 cursors = ~2048 serialized
// cross-XCD RMWs per line (376 us). v3 has ZERO global atomics.
// ---------------------------------------------------------------------------

// 1) per-block bucket histogram of its edge chunk -> H[block][NBUK]
__global__ __launch_bounds__(256) void hist_kernel(const int* __restrict__ dst,
                                                   int* __restrict__ H,
                                                   int E, int chunk) {
    __shared__ int h[NBUK];
    for (int i = threadIdx.x; i < NBUK; i += 256) h[i] = 0;
    __syncthreads();
    const int b = blockIdx.x;
    const int s0 = b * chunk, s1 = min(E, s0 + chunk);
    for (int i = s0 + threadIdx.x; i < s1; i += 256)
        atomicAdd(&h[dst[i] >> 7], 1);
    __syncthreads();
    for (int i = threadIdx.x; i < NBUK; i += 256)
        H[b * NBUK + i] = h[i];
}

// 2) column-scan H (thread = bucket, loop over blocks: coalesced), then scan
//    bucket totals -> boffs. H[b][k] becomes block-b's exclusive offset in k.
__global__ __launch_bounds__(1024) void scan2(int* __restrict__ H,
                                              int* __restrict__ boffs, int E) {
    __shared__ int tot[1024];
    const int k = threadIdx.x;
    int sum = 0;
    if (k < NBUK) {
        for (int b = 0; b < NBLK; b++) {
            const int v = H[b * NBUK + k];
            H[b * NBUK + k] = sum;  // exclusive within column
            sum += v;
        }
    }
    tot[k] = (k < NBUK) ? sum : 0;
    __syncthreads();
    for (int d = 1; d < 1024; d <<= 1) {
        const int u = (k >= d) ? tot[k - d] : 0;
        __syncthreads();
        tot[k] += u;
        __syncthreads();
    }
    if (k < NBUK) boffs[k] = tot[k] - sum;  // exclusive base
    if (k == 0) boffs[NBUK] = E;
}

// 3) scatter packed (dstlo<<20 | src) via LDS cursors; each (block,bucket)
//    run is contiguous (~64 B) and written by one CU -> full-line writebacks.
__global__ __launch_bounds__(256) void scatter2(const int* __restrict__ src,
                                                const int* __restrict__ dst,
                                                const int* __restrict__ H,
                                                const int* __restrict__ boffs,
                                                unsigned* __restrict__ pairs,
                                                int E, int chunk) {
    __shared__ int cur[NBUK];
    const int b = blockIdx.x;
    for (int i = threadIdx.x; i < NBUK; i += 256)
        cur[i] = boffs[i] + H[b * NBUK + i];
    __syncthreads();
    const int s0 = b * chunk, s1 = min(E, s0 + chunk);
    for (int i = s0 + threadIdx.x; i < s1; i += 256) {
        const int d = dst[i];
        const int p = atomicAdd(&cur[d >> 7], 1);
        pairs[p] = ((unsigned)(d & 127) << 20) | (unsigned)src[i];
    }
}

// 4) per-bucket counting sort in LDS; csr/offs writes sequential (unchanged).
__global__ __launch_bounds__(256) void bucket_sort(const unsigned* __restrict__ pairs,
                                                   const int* __restrict__ boffs,
                                                   int* __restrict__ offs,
                                                   int* __restrict__ csr) {
    __shared__ int cnt[128], loffs[128], lcur[128];
    const int b = blockIdx.x, t = threadIdx.x;
    const int e0 = boffs[b], e1 = boffs[b + 1];
    const int node0 = b << 7;
    const int nnode = min(128, NN - node0);
    if (t < 128) cnt[t] = 0;
    __syncthreads();
    for (int i = e0 + t; i < e1; i += 256) atomicAdd(&cnt[pairs[i] >> 20], 1);
    __syncthreads();
    if (t < 128) loffs[t] = cnt[t];
    __syncthreads();
    for (int d = 1; d < 128; d <<= 1) {
        int u = (t >= d && t < 128) ? loffs[t - d] : 0;
        __syncthreads();
        if (t < 128) loffs[t] += u;
        __syncthreads();
    }
    if (t < 128) {
        const int ex = loffs[t] - cnt[t];  // exclusive
        lcur[t] = e0 + ex;
        if (t < nnode) offs[node0 + t] = e0 + ex;
    }
    if (b == NBUK - 1 && t == 0) offs[NN] = e1;
    __syncthreads();
    for (int i = e0 + t; i < e1; i += 256) {
        const unsigned v = pairs[i];
        const int p = atomicAdd(&lcur[v >> 20], 1);
        csr[p] = (int)(v & 0xFFFFFu);
    }
}

// ---------------------------------------------------------------------------
// prepass: fp32 -> bf16 convert (4 elems/thread)
// ---------------------------------------------------------------------------
__global__ void cvt_kernel(const float* __restrict__ X, ushort_t* __restrict__ Y, int n4) {
    int i = blockIdx.x * blockDim.x + threadIdx.x;
    if (i < n4) {
        float4 v = ((const float4*)X)[i];
        us4 o;
        o.x = f2b(v.x); o.y = f2b(v.y); o.z = f2b(v.z); o.w = f2b(v.w);
        ((us4*)Y)[i] = o;
    }
}

// ---------------------------------------------------------------------------
// prepass: all four W [k][n] fp32 -> WT [n][k] bf16 in one launch (64 blocks)
// ---------------------------------------------------------------------------
__global__ __launch_bounds__(256) void wt_all(
    const float* __restrict__ Wa, const float* __restrict__ Wb,
    const float* __restrict__ Wc, const float* __restrict__ Wd,
    ushort_t* __restrict__ Oa, ushort_t* __restrict__ Ob,
    ushort_t* __restrict__ Oc, ushort_t* __restrict__ Od) {
    __shared__ float tile[32][33];
    const int m = blockIdx.x >> 4;
    const int b = blockIdx.x & 15;
    const float* W = (m == 0) ? Wa : (m == 1) ? Wb : (m == 2) ? Wc : Wd;
    ushort_t* WT = (m == 0) ? Oa : (m == 1) ? Ob : (m == 2) ? Oc : Od;
    const int by = (b >> 2) * 32;  // k base
    const int bx = (b & 3) * 32;   // n base
    const int tx = threadIdx.x & 31, ty = threadIdx.x >> 5;  // 32 x 8
    for (int i = 0; i < 32; i += 8)
        tile[ty + i][tx] = W[(by + ty + i) * F + bx + tx];
    __syncthreads();
    for (int i = 0; i < 32; i += 8)
        WT[(bx + ty + i) * F + by + tx] = f2b(tile[tx][ty + i]);
}

// ---------------------------------------------------------------------------
// fused SAGE layer (bf16 MFMA) — unchanged from round 4 (passed, absmax .031)
// ---------------------------------------------------------------------------
template <typename TOUT>
__device__ __forceinline__ void store1(TOUT* p, float v);
template <> __device__ __forceinline__ void store1<float>(float* p, float v) { *p = v; }
template <> __device__ __forceinline__ void store1<ushort_t>(ushort_t* p, float v) { *p = f2b(v); }

template <typename TOUT>
__global__ __launch_bounds__(256, 6) void sage_layer(
    const ushort_t* __restrict__ Xg,
    const int* __restrict__ offs, const int* __restrict__ csr,
    const ushort_t* __restrict__ WTs, const ushort_t* __restrict__ WTn,
    const float* __restrict__ bias,
    TOUT* __restrict__ out, int relu) {
    __shared__ __align__(16) ushort_t sX[32 * LD];
    __shared__ __align__(16) ushort_t sH[32 * LD];
    const int t = threadIdx.x;
    const int lane = t & 63;
    const int wave = t >> 6;
    const int brow0 = blockIdx.x * 32;

    // Phase 0: stage self rows
    {
        const ushort_t* base = Xg + (size_t)brow0 * F;
        for (int i = t; i < 32 * 16; i += 256) {
            int row = i >> 4, ch = i & 15;
            *(short8*)&sX[row * LD + ch * 8] = *(const short8*)&base[row * F + ch * 8];
        }
    }

    // Phase A: neighbor mean -> sH (4 slots x 16 lanes; unroll 4)
    {
        const int slot = lane >> 4;
        const int cl = lane & 15;
        const int c8 = cl * 8;
#pragma unroll
        for (int rr = 0; rr < 2; rr++) {
            const int rloc = wave * 8 + slot * 2 + rr;
            const int row = brow0 + rloc;
            const int e0 = offs[row], e1 = offs[row + 1];
            float a0[8], a1[8], a2[8], a3[8];
#pragma unroll
            for (int j = 0; j < 8; j++) { a0[j] = a1[j] = a2[j] = a3[j] = 0.f; }
            int e = e0;
            for (; e + 3 < e1; e += 4) {
                const int s0 = csr[e], s1 = csr[e + 1], s2 = csr[e + 2], s3 = csr[e + 3];
                const short8 v0 = *(const short8*)&Xg[(size_t)s0 * F + c8];
                const short8 v1 = *(const short8*)&Xg[(size_t)s1 * F + c8];
                const short8 v2 = *(const short8*)&Xg[(size_t)s2 * F + c8];
                const short8 v3 = *(const short8*)&Xg[(size_t)s3 * F + c8];
#pragma unroll
                for (int j = 0; j < 8; j++) {
                    a0[j] += b2f((ushort_t)v0[j]);
                    a1[j] += b2f((ushort_t)v1[j]);
                    a2[j] += b2f((ushort_t)v2[j]);
                    a3[j] += b2f((ushort_t)v3[j]);
                }
            }
            for (; e < e1; e++) {
                const int s0 = csr[e];
                const short8 v0 = *(const short8*)&Xg[(size_t)s0 * F + c8];
#pragma unroll
                for (int j = 0; j < 8; j++) a0[j] += b2f((ushort_t)v0[j]);
            }
            const float inv = (e1 > e0) ? (1.0f / (float)(e1 - e0)) : 0.f;
            short8 o;
#pragma unroll
            for (int j = 0; j < 8; j++)
                o[j] = (short)f2b(((a0[j] + a1[j]) + (a2[j] + a3[j])) * inv);
            *(short8*)&sH[rloc * LD + c8] = o;
        }
    }
    __syncthreads();

    // Phase B: MFMA GEMM (wave strip: 32 rows x 32 cols)
    const int q = lane >> 4, nl = lane & 15;
    const int colbase = wave * 32;
    f32x4 acc00 = (f32x4)0.f, acc01 = (f32x4)0.f, acc10 = (f32x4)0.f, acc11 = (f32x4)0.f;
#pragma unroll
    for (int ks = 0; ks < 4; ks++) {
        const int ko = ks * 32 + q * 8;
        const short8 aS0 = *(const short8*)&sX[nl * LD + ko];
        const short8 aS1 = *(const short8*)&sX[(16 + nl) * LD + ko];
        const short8 aN0 = *(const short8*)&sH[nl * LD + ko];
        const short8 aN1 = *(const short8*)&sH[(16 + nl) * LD + ko];
        const size_t bo0 = (size_t)(colbase + nl) * F + ko;
        const size_t bo1 = (size_t)(colbase + 16 + nl) * F + ko;
        const short8 bS0 = *(const short8*)&WTs[bo0];
        const short8 bS1 = *(const short8*)&WTs[bo1];
        const short8 bN0 = *(const short8*)&WTn[bo0];
        const short8 bN1 = *(const short8*)&WTn[bo1];
        acc00 = __builtin_amdgcn_mfma_f32_16x16x32_bf16(aS0, bS0, acc00, 0, 0, 0);
        acc00 = __builtin_amdgcn_mfma_f32_16x16x32_bf16(aN0, bN0, acc00, 0, 0, 0);
        acc01 = __builtin_amdgcn_mfma_f32_16x16x32_bf16(aS0, bS1, acc01, 0, 0, 0);
        acc01 = __builtin_amdgcn_mfma_f32_16x16x32_bf16(aN0, bN1, acc01, 0, 0, 0);
        acc10 = __builtin_amdgcn_mfma_f32_16x16x32_bf16(aS1, bS0, acc10, 0, 0, 0);
        acc10 = __builtin_amdgcn_mfma_f32_16x16x32_bf16(aN1, bN0, acc10, 0, 0, 0);
        acc11 = __builtin_amdgcn_mfma_f32_16x16x32_bf16(aS1, bS1, acc11, 0, 0, 0);
        acc11 = __builtin_amdgcn_mfma_f32_16x16x32_bf16(aN1, bN1, acc11, 0, 0, 0);
    }

    // Epilogue: C/D layout col=lane&15, row=(lane>>4)*4+reg
    const float b0 = bias[colbase + nl];
    const float b1 = bias[colbase + 16 + nl];
#pragma unroll
    for (int r = 0; r < 4; r++) {
        const int orow0 = brow0 + q * 4 + r;
        const int orow1 = brow0 + 16 + q * 4 + r;
        float v00 = acc00[r] + b0, v01 = acc01[r] + b1;
        float v10 = acc10[r] + b0, v11 = acc11[r] + b1;
        if (relu) {
            v00 = fmaxf(v00, 0.f); v01 = fmaxf(v01, 0.f);
            v10 = fmaxf(v10, 0.f); v11 = fmaxf(v11, 0.f);
        }
        store1<TOUT>(&out[(size_t)orow0 * F + colbase + nl], v00);
        store1<TOUT>(&out[(size_t)orow0 * F + colbase + 16 + nl], v01);
        store1<TOUT>(&out[(size_t)orow1 * F + colbase + nl], v10);
        store1<TOUT>(&out[(size_t)orow1 * F + colbase + 16 + nl], v11);
    }
}

// ---------------------------------------------------------------------------
extern "C" void kernel_launch(void* const* d_in, const int* in_sizes, int n_in,
                              void* d_out, int out_size, void* d_ws, size_t ws_size,
                              hipStream_t stream) {
    const float* x = (const float*)d_in[0];
    const int* src = (const int*)d_in[1];
    const int* dst = (const int*)d_in[2];
    const float* W1s = (const float*)d_in[3];
    const float* W1n = (const float*)d_in[4];
    const float* b1 = (const float*)d_in[5];
    const float* W2s = (const float*)d_in[6];
    const float* W2n = (const float*)d_in[7];
    const float* b2 = (const float*)d_in[8];
    float* out = (float*)d_out;

    const int E = in_sizes[1];
    const int N = NN;
    const int E4 = (E + 3) & ~3;
    const int chunk = (E + NBLK - 1) / NBLK;  // 12500

    // ws layout (~40 MB < proven-safe budget):
    //   pairs[E] u32 | csr[E] int | h1[N*F] bf16 | WT 4*F*F bf16 |
    //   offs[N+1] | H[NBLK*NBUK] | boffs[NBUK+1]
    unsigned* pairs = (unsigned*)d_ws;
    int* csr = (int*)(pairs + E4);
    ushort_t* h1 = (ushort_t*)(csr + E4);
    ushort_t* WT1s = h1 + (size_t)N * F;
    ushort_t* WT1n = WT1s + F * F;
    ushort_t* WT2s = WT1n + F * F;
    ushort_t* WT2n = WT2s + F * F;
    int* offs = (int*)(WT2n + F * F);
    int* H = offs + (N + 1);
    int* boffs = H + NBLK * NBUK;
    // x_bf16 lives in d_out: dead by the time layer 2 overwrites d_out.
    ushort_t* xb = (ushort_t*)d_out;

    // CSR build (no global atomics anywhere)
    hist_kernel<<<NBLK, 256, 0, stream>>>(dst, H, E, chunk);
    scan2<<<1, 1024, 0, stream>>>(H, boffs, E);
    scatter2<<<NBLK, 256, 0, stream>>>(src, dst, H, boffs, pairs, E, chunk);
    bucket_sort<<<NBUK, 256, 0, stream>>>(pairs, boffs, offs, csr);

    // prepasses: x -> bf16 (into d_out), weights -> bf16 transposed
    cvt_kernel<<<(N * F / 4 + 255) / 256, 256, 0, stream>>>(x, xb, N * F / 4);
    wt_all<<<64, 256, 0, stream>>>(W1s, W1n, W2s, W2n, WT1s, WT1n, WT2s, WT2n);

    // layer 1: bf16 in (xb), bf16 h1 out, relu
    sage_layer<ushort_t><<<N / 32, 256, 0, stream>>>(
        xb, offs, csr, WT1s, WT1n, b1, h1, 1);
    // layer 2: bf16 in (h1), fp32 out
    sage_layer<float><<<N / 32, 256, 0, stream>>>(
        h1, offs, csr, WT2s, WT2n, b2, out, 0);
}

// Round 7
// 363.220 us; speedup vs baseline: 1.9669x; 1.0144x over previous
//
#include <hip/hip_runtime.h>

#define F 128
#define NN 100000
#define NBUK 782   // ceil(NN/128), 128 nodes per bucket
#define NBLK 256   // sort chunks (full-GPU grids; ~32B runs per (blk,bucket))
#define LD 136     // padded LDS row stride in bf16 elems (272 B)
#define N4 (NN * F / 4)   // 3.2M float4's in x
#define N4A (N4 / 2)      // cvt half done in K1, half in K2

typedef __attribute__((ext_vector_type(8))) short short8;   // 8 bf16 = 16 B
typedef __attribute__((ext_vector_type(4))) float f32x4;
typedef __attribute__((ext_vector_type(4))) unsigned short us4;
typedef unsigned short ushort_t;

// ---------------------------------------------------------------------------
// bf16 helpers (RNE)
// ---------------------------------------------------------------------------
__device__ __forceinline__ ushort_t f2b(float f) {
    union { float f; unsigned u; } x;
    x.f = f;
    unsigned r = x.u + 0x7fffu + ((x.u >> 16) & 1u);
    return (ushort_t)(r >> 16);
}
__device__ __forceinline__ float b2f(ushort_t u) {
    union { unsigned u; float f; } x;
    x.u = ((unsigned)u) << 16;
    return x.f;
}

// ---------------------------------------------------------------------------
// K1 (fused): blocks [0,NBLK): per-chunk bucket histogram -> H[blk][NBUK]
//             blocks [NBLK,NBLK+64): W -> WT bf16 transpose (4 matrices)
//             blocks [NBLK+64, ...): x -> bf16 convert, first half
// ---------------------------------------------------------------------------
__global__ __launch_bounds__(256) void k1_fused(
    const int* __restrict__ dst, int* __restrict__ H, int E, int chunk,
    const float* __restrict__ Wa, const float* __restrict__ Wb,
    const float* __restrict__ Wc, const float* __restrict__ Wd,
    ushort_t* __restrict__ Oa, ushort_t* __restrict__ Ob,
    ushort_t* __restrict__ Oc, ushort_t* __restrict__ Od,
    const float* __restrict__ X, ushort_t* __restrict__ Y) {
    __shared__ union {
        int h[NBUK];
        float tile[32][33];
    } u;
    const int blk = blockIdx.x;
    if (blk < NBLK) {
        // histogram
        for (int i = threadIdx.x; i < NBUK; i += 256) u.h[i] = 0;
        __syncthreads();
        const int s0 = blk * chunk, s1 = min(E, s0 + chunk);
        for (int i = s0 + threadIdx.x; i < s1; i += 256)
            atomicAdd(&u.h[dst[i] >> 7], 1);
        __syncthreads();
        for (int i = threadIdx.x; i < NBUK; i += 256)
            H[blk * NBUK + i] = u.h[i];
    } else if (blk < NBLK + 64) {
        // weight transpose+convert
        const int m = (blk - NBLK) >> 4;
        const int b = (blk - NBLK) & 15;
        const float* W = (m == 0) ? Wa : (m == 1) ? Wb : (m == 2) ? Wc : Wd;
        ushort_t* WT = (m == 0) ? Oa : (m == 1) ? Ob : (m == 2) ? Oc : Od;
        const int by = (b >> 2) * 32;
        const int bx = (b & 3) * 32;
        const int tx = threadIdx.x & 31, ty = threadIdx.x >> 5;
        for (int i = 0; i < 32; i += 8)
            u.tile[ty + i][tx] = W[(by + ty + i) * F + bx + tx];
        __syncthreads();
        for (int i = 0; i < 32; i += 8)
            WT[(bx + ty + i) * F + by + tx] = f2b(u.tile[tx][ty + i]);
    } else {
        // cvt first half
        const int i = (blk - NBLK - 64) * 256 + threadIdx.x;
        if (i < N4A) {
            float4 v = ((const float4*)X)[i];
            us4 o;
            o.x = f2b(v.x); o.y = f2b(v.y); o.z = f2b(v.z); o.w = f2b(v.w);
            ((us4*)Y)[i] = o;
        }
    }
}

// ---------------------------------------------------------------------------
// K2 (fused, 1024 thr): block 0: column-scan H + bucket-total scan -> boffs
//                       blocks >=1: cvt second half
// ---------------------------------------------------------------------------
__global__ __launch_bounds__(1024) void k2_fused(
    int* __restrict__ H, int* __restrict__ boffs, int E,
    const float* __restrict__ X, ushort_t* __restrict__ Y) {
    if (blockIdx.x == 0) {
        __shared__ int tot[1024];
        const int k = threadIdx.x;
        int sum = 0;
        if (k < NBUK) {
#pragma unroll 1
            for (int b = 0; b < NBLK; b += 4) {  // batched loads, serial prefix
                const int v0 = H[(b + 0) * NBUK + k];
                const int v1 = H[(b + 1) * NBUK + k];
                const int v2 = H[(b + 2) * NBUK + k];
                const int v3 = H[(b + 3) * NBUK + k];
                H[(b + 0) * NBUK + k] = sum; sum += v0;
                H[(b + 1) * NBUK + k] = sum; sum += v1;
                H[(b + 2) * NBUK + k] = sum; sum += v2;
                H[(b + 3) * NBUK + k] = sum; sum += v3;
            }
        }
        tot[k] = (k < NBUK) ? sum : 0;
        __syncthreads();
        for (int d = 1; d < 1024; d <<= 1) {
            const int u = (k >= d) ? tot[k - d] : 0;
            __syncthreads();
            tot[k] += u;
            __syncthreads();
        }
        if (k < NBUK) boffs[k] = tot[k] - sum;  // exclusive base
        if (k == 0) boffs[NBUK] = E;
    } else {
        const int i = N4A + (blockIdx.x - 1) * 1024 + threadIdx.x;
        if (i < N4) {
            float4 v = ((const float4*)X)[i];
            us4 o;
            o.x = f2b(v.x); o.y = f2b(v.y); o.z = f2b(v.z); o.w = f2b(v.w);
            ((us4*)Y)[i] = o;
        }
    }
}

// ---------------------------------------------------------------------------
// scatter packed (dstlo<<20 | src) via LDS cursors; per-(block,bucket) runs
// are contiguous and single-CU (no cross-XCD line ping-pong, no glb atomics).
// ---------------------------------------------------------------------------
__global__ __launch_bounds__(256) void scatter2(const int* __restrict__ src,
                                                const int* __restrict__ dst,
                                                const int* __restrict__ H,
                                                const int* __restrict__ boffs,
                                                unsigned* __restrict__ pairs,
                                                int E, int chunk) {
    __shared__ int cur[NBUK];
    const int b = blockIdx.x;
    for (int i = threadIdx.x; i < NBUK; i += 256)
        cur[i] = boffs[i] + H[b * NBUK + i];
    __syncthreads();
    const int s0 = b * chunk, s1 = min(E, s0 + chunk);
    for (int i = s0 + threadIdx.x; i < s1; i += 256) {
        const int d = dst[i];
        const int p = atomicAdd(&cur[d >> 7], 1);
        pairs[p] = ((unsigned)(d & 127) << 20) | (unsigned)src[i];
    }
}

// ---------------------------------------------------------------------------
// per-bucket counting sort in LDS; csr/offs writes sequential.
// ---------------------------------------------------------------------------
__global__ __launch_bounds__(256) void bucket_sort(const unsigned* __restrict__ pairs,
                                                   const int* __restrict__ boffs,
                                                   int* __restrict__ offs,
                                                   int* __restrict__ csr) {
    __shared__ int cnt[128], loffs[128], lcur[128];
    const int b = blockIdx.x, t = threadIdx.x;
    const int e0 = boffs[b], e1 = boffs[b + 1];
    const int node0 = b << 7;
    const int nnode = min(128, NN - node0);
    if (t < 128) cnt[t] = 0;
    __syncthreads();
    for (int i = e0 + t; i < e1; i += 256) atomicAdd(&cnt[pairs[i] >> 20], 1);
    __syncthreads();
    if (t < 128) loffs[t] = cnt[t];
    __syncthreads();
    for (int d = 1; d < 128; d <<= 1) {
        int u = (t >= d && t < 128) ? loffs[t - d] : 0;
        __syncthreads();
        if (t < 128) loffs[t] += u;
        __syncthreads();
    }
    if (t < 128) {
        const int ex = loffs[t] - cnt[t];  // exclusive
        lcur[t] = e0 + ex;
        if (t < nnode) offs[node0 + t] = e0 + ex;
    }
    if (b == NBUK - 1 && t == 0) offs[NN] = e1;
    __syncthreads();
    for (int i = e0 + t; i < e1; i += 256) {
        const unsigned v = pairs[i];
        const int p = atomicAdd(&lcur[v >> 20], 1);
        csr[p] = (int)(v & 0xFFFFFu);
    }
}

// ---------------------------------------------------------------------------
// fused SAGE layer (bf16 MFMA): out = X@Ws + mean_neigh(X)@Wn + b (+relu)
// 8 blocks/CU (launch_bounds(256,8); LDS 17.4KB*8=139KB, VGPR<=64).
// bf16 output goes through an LDS bounce -> coalesced short8 row stores
// (round-6 counter: 50MB WRITE for 25.6MB h1 = 2x partial-line amp).
// ---------------------------------------------------------------------------
template <typename TOUT>
__global__ __launch_bounds__(256, 8) void sage_layer(
    const ushort_t* __restrict__ Xg,
    const int* __restrict__ offs, const int* __restrict__ csr,
    const ushort_t* __restrict__ WTs, const ushort_t* __restrict__ WTn,
    const float* __restrict__ bias,
    TOUT* __restrict__ out, int relu) {
    __shared__ __align__(16) ushort_t sX[32 * LD];
    __shared__ __align__(16) ushort_t sH[32 * LD];
    const int t = threadIdx.x;
    const int lane = t & 63;
    const int wave = t >> 6;
    const int brow0 = blockIdx.x * 32;

    // Phase 0: stage self rows
    {
        const ushort_t* base = Xg + (size_t)brow0 * F;
        for (int i = t; i < 32 * 16; i += 256) {
            int row = i >> 4, ch = i & 15;
            *(short8*)&sX[row * LD + ch * 8] = *(const short8*)&base[row * F + ch * 8];
        }
    }

    // Phase A: neighbor mean -> sH (4 slots x 16 lanes; unroll 4)
    {
        const int slot = lane >> 4;
        const int cl = lane & 15;
        const int c8 = cl * 8;
#pragma unroll
        for (int rr = 0; rr < 2; rr++) {
            const int rloc = wave * 8 + slot * 2 + rr;
            const int row = brow0 + rloc;
            const int e0 = offs[row], e1 = offs[row + 1];
            float a0[8], a1[8], a2[8], a3[8];
#pragma unroll
            for (int j = 0; j < 8; j++) { a0[j] = a1[j] = a2[j] = a3[j] = 0.f; }
            int e = e0;
            for (; e + 3 < e1; e += 4) {
                const int s0 = csr[e], s1 = csr[e + 1], s2 = csr[e + 2], s3 = csr[e + 3];
                const short8 v0 = *(const short8*)&Xg[(size_t)s0 * F + c8];
                const short8 v1 = *(const short8*)&Xg[(size_t)s1 * F + c8];
                const short8 v2 = *(const short8*)&Xg[(size_t)s2 * F + c8];
                const short8 v3 = *(const short8*)&Xg[(size_t)s3 * F + c8];
#pragma unroll
                for (int j = 0; j < 8; j++) {
                    a0[j] += b2f((ushort_t)v0[j]);
                    a1[j] += b2f((ushort_t)v1[j]);
                    a2[j] += b2f((ushort_t)v2[j]);
                    a3[j] += b2f((ushort_t)v3[j]);
                }
            }
            for (; e < e1; e++) {
                const int s0 = csr[e];
                const short8 v0 = *(const short8*)&Xg[(size_t)s0 * F + c8];
#pragma unroll
                for (int j = 0; j < 8; j++) a0[j] += b2f((ushort_t)v0[j]);
            }
            const float inv = (e1 > e0) ? (1.0f / (float)(e1 - e0)) : 0.f;
            short8 o;
#pragma unroll
            for (int j = 0; j < 8; j++)
                o[j] = (short)f2b(((a0[j] + a1[j]) + (a2[j] + a3[j])) * inv);
            *(short8*)&sH[rloc * LD + c8] = o;
        }
    }
    __syncthreads();

    // Phase B: MFMA GEMM (wave strip: 32 rows x 32 cols)
    const int q = lane >> 4, nl = lane & 15;
    const int colbase = wave * 32;
    f32x4 acc00 = (f32x4)0.f, acc01 = (f32x4)0.f, acc10 = (f32x4)0.f, acc11 = (f32x4)0.f;
#pragma unroll
    for (int ks = 0; ks < 4; ks++) {
        const int ko = ks * 32 + q * 8;
        const short8 aS0 = *(const short8*)&sX[nl * LD + ko];
        const short8 aS1 = *(const short8*)&sX[(16 + nl) * LD + ko];
        const short8 aN0 = *(const short8*)&sH[nl * LD + ko];
        const short8 aN1 = *(const short8*)&sH[(16 + nl) * LD + ko];
        const size_t bo0 = (size_t)(colbase + nl) * F + ko;
        const size_t bo1 = (size_t)(colbase + 16 + nl) * F + ko;
        const short8 bS0 = *(const short8*)&WTs[bo0];
        const short8 bS1 = *(const short8*)&WTs[bo1];
        const short8 bN0 = *(const short8*)&WTn[bo0];
        const short8 bN1 = *(const short8*)&WTn[bo1];
        acc00 = __builtin_amdgcn_mfma_f32_16x16x32_bf16(aS0, bS0, acc00, 0, 0, 0);
        acc00 = __builtin_amdgcn_mfma_f32_16x16x32_bf16(aN0, bN0, acc00, 0, 0, 0);
        acc01 = __builtin_amdgcn_mfma_f32_16x16x32_bf16(aS0, bS1, acc01, 0, 0, 0);
        acc01 = __builtin_amdgcn_mfma_f32_16x16x32_bf16(aN0, bN1, acc01, 0, 0, 0);
        acc10 = __builtin_amdgcn_mfma_f32_16x16x32_bf16(aS1, bS0, acc10, 0, 0, 0);
        acc10 = __builtin_amdgcn_mfma_f32_16x16x32_bf16(aN1, bN0, acc10, 0, 0, 0);
        acc11 = __builtin_amdgcn_mfma_f32_16x16x32_bf16(aS1, bS1, acc11, 0, 0, 0);
        acc11 = __builtin_amdgcn_mfma_f32_16x16x32_bf16(aN1, bN1, acc11, 0, 0, 0);
    }

    // Epilogue: C/D layout col=lane&15, row=(lane>>4)*4+reg
    const float b0 = bias[colbase + nl];
    const float b1 = bias[colbase + 16 + nl];
    if constexpr (sizeof(TOUT) == 2) {
        // bf16: bounce via LDS (reuse sX) -> coalesced short8 row stores
        __syncthreads();  // all waves done reading sX in phase B
#pragma unroll
        for (int r = 0; r < 4; r++) {
            const int lr0 = q * 4 + r, lr1 = 16 + q * 4 + r;
            float v00 = acc00[r] + b0, v01 = acc01[r] + b1;
            float v10 = acc10[r] + b0, v11 = acc11[r] + b1;
            if (relu) {
                v00 = fmaxf(v00, 0.f); v01 = fmaxf(v01, 0.f);
                v10 = fmaxf(v10, 0.f); v11 = fmaxf(v11, 0.f);
            }
            sX[lr0 * LD + colbase + nl] = f2b(v00);
            sX[lr0 * LD + colbase + 16 + nl] = f2b(v01);
            sX[lr1 * LD + colbase + nl] = f2b(v10);
            sX[lr1 * LD + colbase + 16 + nl] = f2b(v11);
        }
        __syncthreads();
        TOUT* base = out + (size_t)brow0 * F;
        for (int i = t; i < 32 * 16; i += 256) {
            int row = i >> 4, ch = i & 15;
            *(short8*)&base[row * F + ch * 8] = *(const short8*)&sX[row * LD + ch * 8];
        }
    } else {
#pragma unroll
        for (int r = 0; r < 4; r++) {
            const int orow0 = brow0 + q * 4 + r;
            const int orow1 = brow0 + 16 + q * 4 + r;
            float v00 = acc00[r] + b0, v01 = acc01[r] + b1;
            float v10 = acc10[r] + b0, v11 = acc11[r] + b1;
            if (relu) {
                v00 = fmaxf(v00, 0.f); v01 = fmaxf(v01, 0.f);
                v10 = fmaxf(v10, 0.f); v11 = fmaxf(v11, 0.f);
            }
            out[(size_t)orow0 * F + colbase + nl] = v00;
            out[(size_t)orow0 * F + colbase + 16 + nl] = v01;
            out[(size_t)orow1 * F + colbase + nl] = v10;
            out[(size_t)orow1 * F + colbase + 16 + nl] = v11;
        }
    }
}

// ---------------------------------------------------------------------------
extern "C" void kernel_launch(void* const* d_in, const int* in_sizes, int n_in,
                              void* d_out, int out_size, void* d_ws, size_t ws_size,
                              hipStream_t stream) {
    const float* x = (const float*)d_in[0];
    const int* src = (const int*)d_in[1];
    const int* dst = (const int*)d_in[2];
    const float* W1s = (const float*)d_in[3];
    const float* W1n = (const float*)d_in[4];
    const float* b1 = (const float*)d_in[5];
    const float* W2s = (const float*)d_in[6];
    const float* W2n = (const float*)d_in[7];
    const float* b2 = (const float*)d_in[8];
    float* out = (float*)d_out;

    const int E = in_sizes[1];
    const int N = NN;
    const int E4 = (E + 3) & ~3;
    const int chunk = (E + NBLK - 1) / NBLK;

    // ws layout (~40 MB < proven-safe budget):
    //   pairs[E] u32 | csr[E] int | h1[N*F] bf16 | WT 4*F*F bf16 |
    //   offs[N+1] | H[NBLK*NBUK] | boffs[NBUK+1]
    unsigned* pairs = (unsigned*)d_ws;
    int* csr = (int*)(pairs + E4);
    ushort_t* h1 = (ushort_t*)(csr + E4);
    ushort_t* WT1s = h1 + (size_t)N * F;
    ushort_t* WT1n = WT1s + F * F;
    ushort_t* WT2s = WT1n + F * F;
    ushort_t* WT2n = WT2s + F * F;
    int* offs = (int*)(WT2n + F * F);
    int* H = offs + (N + 1);
    int* boffs = H + NBLK * NBUK;
    // x_bf16 lives in d_out: dead by the time layer 2 overwrites d_out.
    ushort_t* xb = (ushort_t*)d_out;

    // K1: hist (NBLK blocks) + weight transpose (64) + cvt half A
    const int cvtA_blocks = (N4A + 255) / 256;
    k1_fused<<<NBLK + 64 + cvtA_blocks, 256, 0, stream>>>(
        dst, H, E, chunk, W1s, W1n, W2s, W2n, WT1s, WT1n, WT2s, WT2n, x, xb);
    // K2: scan (block 0) + cvt half B
    const int cvtB_blocks = (N4 - N4A + 1023) / 1024;
    k2_fused<<<1 + cvtB_blocks, 1024, 0, stream>>>(H, boffs, E, x, xb);
    scatter2<<<NBLK, 256, 0, stream>>>(src, dst, H, boffs, pairs, E, chunk);
    bucket_sort<<<NBUK, 256, 0, stream>>>(pairs, boffs, offs, csr);

    // layer 1: bf16 in (xb), bf16 h1 out, relu
    sage_layer<ushort_t><<<N / 32, 256, 0, stream>>>(
        xb, offs, csr, WT1s, WT1n, b1, h1, 1);
    // layer 2: bf16 in (h1), fp32 out
    sage_layer<float><<<N / 32, 256, 0, stream>>>(
        h1, offs, csr, WT2s, WT2n, b2, out, 0);
}